// Round 2
// baseline (12492.307 us; speedup 1.0000x reference)
//
#include <hip/hip_runtime.h>
#include <math.h>

#define BATCH 64
#define TLEN 512
#define EMB 256
#define HID 256          // per-direction hidden
#define G4 1024          // 4*HID
#define KTAG 12
#define START_TAG 10
#define STOP_TAG 11
#define NEGV -10000.0f

// ---------------------------------------------------------------------------
// K1: fused embedding gather + input projection, both directions.
// C[r][g2] = emb[token[r]] . W_ih[g2] + b_ih[g2] + b_hh[g2]
// ---------------------------------------------------------------------------
#define MT 128
#define NT 128
#define KC 32
#define LDP 132

__global__ __launch_bounds__(256) void proj_kernel(
    const int* __restrict__ sentence, const float* __restrict__ emb,
    const float* __restrict__ Wf_ih, const float* __restrict__ Wb_ih,
    const float* __restrict__ bf_ih, const float* __restrict__ bf_hh,
    const float* __restrict__ bb_ih, const float* __restrict__ bb_hh,
    float* __restrict__ xf, float* __restrict__ xb) {
    int mtile = blockIdx.x;
    int ntile = blockIdx.y;
    int tid = threadIdx.x;

    __shared__ float As[KC][LDP];
    __shared__ float Bs[KC][LDP];
    __shared__ int tok[MT];

    int g2base = ntile * NT;
    const bool fwd = (g2base < 1024);
    const float* Wih = fwd ? Wf_ih : Wb_ih;
    const float* bia = fwd ? bf_ih : bb_ih;
    const float* bib = fwd ? bf_hh : bb_hh;
    float* dst       = fwd ? xf    : xb;
    int glb = g2base & 1023;

    if (tid < MT) tok[tid] = sentence[(size_t)mtile * MT + tid];
    __syncthreads();

    float acc[8][8];
#pragma unroll
    for (int i = 0; i < 8; ++i)
#pragma unroll
        for (int jj = 0; jj < 8; ++jj) acc[i][jj] = 0.f;

    int m0 = (tid & 15) * 8;
    int n0 = (tid >> 4) * 8;
    int lr = tid >> 3;
    int lk = (tid & 7) * 4;

    for (int k0 = 0; k0 < EMB; k0 += KC) {
#pragma unroll
        for (int i = 0; i < 4; ++i) {
            int r = lr + 32 * i;
            float4 v = *(const float4*)(emb + (size_t)tok[r] * EMB + k0 + lk);
            As[lk + 0][r] = v.x; As[lk + 1][r] = v.y;
            As[lk + 2][r] = v.z; As[lk + 3][r] = v.w;
            float4 w = *(const float4*)(Wih + (size_t)(glb + r) * EMB + k0 + lk);
            Bs[lk + 0][r] = w.x; Bs[lk + 1][r] = w.y;
            Bs[lk + 2][r] = w.z; Bs[lk + 3][r] = w.w;
        }
        __syncthreads();
#pragma unroll
        for (int kk = 0; kk < KC; ++kk) {
            float4 a0 = *(const float4*)&As[kk][m0];
            float4 a1 = *(const float4*)&As[kk][m0 + 4];
            float4 b0 = *(const float4*)&Bs[kk][n0];
            float4 b1 = *(const float4*)&Bs[kk][n0 + 4];
            float av[8] = {a0.x, a0.y, a0.z, a0.w, a1.x, a1.y, a1.z, a1.w};
            float bv[8] = {b0.x, b0.y, b0.z, b0.w, b1.x, b1.y, b1.z, b1.w};
#pragma unroll
            for (int i = 0; i < 8; ++i)
#pragma unroll
                for (int jj = 0; jj < 8; ++jj) acc[i][jj] += av[i] * bv[jj];
        }
        __syncthreads();
    }

#pragma unroll
    for (int jj = 0; jj < 8; ++jj) {
        int gl = glb + n0 + jj;
        float bias = bia[gl] + bib[gl];
#pragma unroll
        for (int i = 0; i < 8; ++i) {
            size_t r = (size_t)mtile * MT + m0 + i;
            dst[r * (size_t)G4 + gl] = acc[i][jj] + bias;
        }
    }
}

// ---------------------------------------------------------------------------
// K2: cooperative LSTM scan. 256 blocks = 16 groups (2 dir x 8 batch-groups)
// x 16 hidden-slices. W_hh lives in VGPRs (64/thread). Per step, the 16
// slice-blocks of a group exchange h (8 batches x 256 dims) through a
// double-buffered global region guarded by a monotonic agent-scope flag.
// blockIdx remap: group-id = blk & 15 so all 16 members share blk%8 (XCD
// locality heuristic only; correctness is agent-scope).
//
// Thread map (256 thr): tid = j*16 + gate*4 + kq
//   j  in [0,16): hidden dim within slice
//   gate in [0,4): i,f,g,o
//   kq in [0,4): 64-wide contraction chunk
// Reduce over kq: __shfl_xor 1,2 (intra-quad). Gate gather: __shfl_xor 4,8.
// All 16 lanes of a j-group compute activations redundantly (keeps c in regs
// everywhere, no extra broadcast).
// ---------------------------------------------------------------------------
__device__ __forceinline__ float agent_load_f(const float* p) {
    return __hip_atomic_load(p, __ATOMIC_RELAXED, __HIP_MEMORY_SCOPE_AGENT);
}
__device__ __forceinline__ void agent_store_f(float* p, float v) {
    __hip_atomic_store(p, v, __ATOMIC_RELAXED, __HIP_MEMORY_SCOPE_AGENT);
}

__global__ __launch_bounds__(256) void lstm_scan2(
    const float* __restrict__ xf, const float* __restrict__ xb,
    const float* __restrict__ Wf_hh, const float* __restrict__ Wb_hh,
    float* __restrict__ hglob,          // [16 grp][2 buf][8 bb][256]
    unsigned int* __restrict__ flags,   // [16]
    float* __restrict__ hcat) {
    int blk = blockIdx.x;
    int grp = blk & 15;          // d*8+g  -> members share blk%8
    int s   = blk >> 4;          // slice 0..15
    int d   = grp >> 3;
    int g   = grp & 7;
    int tid = threadIdx.x;
    int kq   = tid & 3;
    int gate = (tid >> 2) & 3;
    int j    = tid >> 4;
    int J    = s * 16 + j;       // global hidden dim
    int wi   = gate * 4 + kq;    // writer-lane id 0..15

    // --- W_hh chunk -> registers (once) ---
    const float* Whh = (d ? Wb_hh : Wf_hh);
    const float* wrow = Whh + (size_t)(gate * 256 + J) * 256 + kq * 64;
    float4 Wr[16];
#pragma unroll
    for (int q = 0; q < 16; ++q) Wr[q] = *(const float4*)(wrow + q * 4);

    const float* x = (d ? xb : xf);
    float* hbuf = hglob + (size_t)grp * 2 * 2048;
    unsigned int* flag = flags + grp;
    const int b0 = g * 8;

    __shared__ float hsL[8 * 272];   // [bb][4 chunks * 68] padded: conflict-free
    float c[8];
#pragma unroll
    for (int bb = 0; bb < 8; ++bb) c[bb] = 0.f;

    for (int i = 0; i < TLEN; ++i) {
        int t = d ? (TLEN - 1 - i) : i;

        // prefetch x for this step (independent of the flag)
        float xv[8];
#pragma unroll
        for (int bb = 0; bb < 8; ++bb)
            xv[bb] = x[((size_t)(b0 + bb) * TLEN + t) * G4 + gate * 256 + J];

        if (i > 0) {
            if (tid == 0) {
                unsigned int target = (unsigned int)i * 16u;
                while (__hip_atomic_load(flag, __ATOMIC_RELAXED,
                                         __HIP_MEMORY_SCOPE_AGENT) < target) {}
            }
            __syncthreads();
            __builtin_amdgcn_fence(__ATOMIC_ACQUIRE, "agent");
            const float* src = hbuf + ((i - 1) & 1) * 2048;
#pragma unroll
            for (int r = 0; r < 8; ++r) {
                float v = agent_load_f(src + r * 256 + tid);
                hsL[r * 272 + (tid >> 6) * 68 + (tid & 63)] = v;
            }
        } else {
#pragma unroll
            for (int r = 0; r < 8; ++r)
                hsL[r * 272 + (tid >> 6) * 68 + (tid & 63)] = 0.f;
        }
        __syncthreads();

#pragma unroll
        for (int bb = 0; bb < 8; ++bb) {
            const float* hp = hsL + bb * 272 + kq * 68;
            float acc = 0.f;
#pragma unroll
            for (int q = 0; q < 16; ++q) {
                float4 h4 = *(const float4*)(hp + q * 4);
                float4 w4 = Wr[q];
                acc += w4.x * h4.x + w4.y * h4.y + w4.z * h4.z + w4.w * h4.w;
            }
            // reduce over kq (intra-quad, DPP)
            acc += __shfl_xor(acc, 1);
            acc += __shfl_xor(acc, 2);
            acc += xv[bb];
            // gather the 4 gate values to every lane
            float a1 = __shfl_xor(acc, 4);
            float a2 = __shfl_xor(acc, 8);
            float a3 = __shfl_xor(a1, 8);
            // value for gate index m sits at xor-offset o = gate^m
            float gi = (gate == 0) ? acc : (gate == 1) ? a1 : (gate == 2) ? a2 : a3;
            int o1 = gate ^ 1;
            float gf = (o1 == 0) ? acc : (o1 == 1) ? a1 : (o1 == 2) ? a2 : a3;
            int o2 = gate ^ 2;
            float gG = (o2 == 0) ? acc : (o2 == 1) ? a1 : (o2 == 2) ? a2 : a3;
            int o3 = gate ^ 3;
            float go = (o3 == 0) ? acc : (o3 == 1) ? a1 : (o3 == 2) ? a2 : a3;

            gi = 1.f / (1.f + expf(-gi));
            gf = 1.f / (1.f + expf(-gf));
            gG = tanhf(gG);
            go = 1.f / (1.f + expf(-go));
            c[bb] = gf * c[bb] + gi * gG;
            float h = go * tanhf(c[bb]);

            if (wi == bb) {
                agent_store_f(hbuf + (i & 1) * 2048 + bb * 256 + J, h);
                hcat[((size_t)t * BATCH + (b0 + bb)) * 512 + (size_t)d * HID + J] = h;
            }
        }

        __syncthreads();          // all h stores issued & drained (vmcnt) before flag
        if (tid == 0)
            __hip_atomic_fetch_add(flag, 1u, __ATOMIC_RELEASE, __HIP_MEMORY_SCOPE_AGENT);
    }
}

// ---------------------------------------------------------------------------
// K3: feats[t,b,k] = hcat[t,b,:] . W_out[k,:] + b_out[k].
// ---------------------------------------------------------------------------
__global__ __launch_bounds__(256) void feats_kernel(
    const float* __restrict__ hcat, const float* __restrict__ Wout,
    const float* __restrict__ bout, float* __restrict__ feats) {
    int wid = threadIdx.x >> 6;
    int lane = threadIdx.x & 63;
    size_t row = (size_t)blockIdx.x * 4 + wid;
    const float* hrow = hcat + row * 512;
    float4 h0 = *(const float4*)(hrow + lane * 8);
    float4 h1 = *(const float4*)(hrow + lane * 8 + 4);
    for (int k2 = 0; k2 < KTAG; ++k2) {
        const float* wr = Wout + (size_t)k2 * 512 + lane * 8;
        float4 w0 = *(const float4*)wr;
        float4 w1 = *(const float4*)(wr + 4);
        float p = h0.x * w0.x + h0.y * w0.y + h0.z * w0.z + h0.w * w0.w
                + h1.x * w1.x + h1.y * w1.y + h1.z * w1.z + h1.w * w1.w;
#pragma unroll
        for (int off = 32; off; off >>= 1) p += __shfl_down(p, off);
        if (lane == 0) feats[row * KTAG + k2] = p + bout[k2];
    }
}

// ---------------------------------------------------------------------------
// K4: Viterbi DP + backtrace. One wave per batch.
// ---------------------------------------------------------------------------
__global__ __launch_bounds__(64) void viterbi_kernel(
    const float* __restrict__ feats, const float* __restrict__ trans,
    const int* __restrict__ slen, float* __restrict__ out) {
    int b = blockIdx.x;
    int lane = threadIdx.x;
    __shared__ unsigned char bp[TLEN][KTAG];

    int len = slen[b];
    float tr[KTAG];
#pragma unroll
    for (int p = 0; p < KTAG; ++p) tr[p] = 0.f;
    if (lane < KTAG) {
#pragma unroll
        for (int p = 0; p < KTAG; ++p) tr[p] = trans[lane * KTAG + p];
    }
    float tstop = (lane < KTAG) ? trans[STOP_TAG * KTAG + lane] : NEGV;
    float dp = (lane == START_TAG) ? 0.f : NEGV;

    float ftn = (lane < KTAG) ? feats[(size_t)b * KTAG + lane] : 0.f;
    for (int t = 0; t < TLEN; ++t) {
        float ftc = ftn;
        if (t + 1 < TLEN && lane < KTAG)
            ftn = feats[((size_t)(t + 1) * BATCH + b) * KTAG + lane];
        float best = -1e30f;
        int arg = 0;
#pragma unroll
        for (int p = 0; p < KTAG; ++p) {
            float dpp = __shfl(dp, p);
            float s = dpp + tr[p];
            if (s > best) { best = s; arg = p; }
        }
        bool m = (t < len);
        if (lane < KTAG) {
            dp = m ? (best + ftc) : dp;
            bp[t][lane] = (unsigned char)(m ? arg : lane);
        }
    }

    float term = dp + tstop;
    float bbest = -1e30f;
    int barg = 0;
#pragma unroll
    for (int p = 0; p < KTAG; ++p) {
        float v = __shfl(term, p);
        if (v > bbest) { bbest = v; barg = p; }
    }
    if (lane == 0) {
        out[b] = bbest;
        float* path = out + BATCH + (size_t)b * TLEN;
        int tag = barg;
        for (int t = TLEN - 1; t >= 0; --t) {
            path[t] = (float)tag;
            tag = bp[t][tag];
        }
    }
}

// ---------------------------------------------------------------------------
extern "C" void kernel_launch(void* const* d_in, const int* in_sizes, int n_in,
                              void* d_out, int out_size, void* d_ws, size_t ws_size,
                              hipStream_t stream) {
    const int*   sentence = (const int*)d_in[0];
    const int*   slen     = (const int*)d_in[1];
    const float* emb      = (const float*)d_in[2];
    const float* Wf_ih    = (const float*)d_in[3];
    const float* Wf_hh    = (const float*)d_in[4];
    const float* bf_ih    = (const float*)d_in[5];
    const float* bf_hh    = (const float*)d_in[6];
    const float* Wb_ih    = (const float*)d_in[7];
    const float* Wb_hh    = (const float*)d_in[8];
    const float* bb_ih    = (const float*)d_in[9];
    const float* bb_hh    = (const float*)d_in[10];
    const float* W_out    = (const float*)d_in[11];
    const float* b_out    = (const float*)d_in[12];
    const float* trans    = (const float*)d_in[13];
    float* out = (float*)d_out;

    char* ws = (char*)d_ws;
    float*        xf    = (float*)(ws);                       // 134,217,728 B
    float*        xb    = (float*)(ws + 134217728ull);        // 134,217,728 B
    float*        hcat  = (float*)(ws + 268435456ull);        //  67,108,864 B
    float*        feats = (float*)(ws + 335544320ull);        //   1,572,864 B
    float*        hglob = (float*)(ws + 337117184ull);        //     262,144 B
    unsigned int* flags = (unsigned int*)(ws + 337379328ull); //          64 B

    hipMemsetAsync(flags, 0, 16 * sizeof(unsigned int), stream);
    hipLaunchKernelGGL(proj_kernel, dim3(256, 16), dim3(256), 0, stream,
                       sentence, emb, Wf_ih, Wb_ih, bf_ih, bf_hh, bb_ih, bb_hh, xf, xb);
    hipLaunchKernelGGL(lstm_scan2, dim3(256), dim3(256), 0, stream,
                       xf, xb, Wf_hh, Wb_hh, hglob, flags, hcat);
    hipLaunchKernelGGL(feats_kernel, dim3(8192), dim3(256), 0, stream,
                       hcat, W_out, b_out, feats);
    hipLaunchKernelGGL(viterbi_kernel, dim3(64), dim3(64), 0, stream,
                       feats, trans, slen, out);
}

// Round 3
// 4185.550 us; speedup vs baseline: 2.9846x; 2.9846x over previous
//
#include <hip/hip_runtime.h>
#include <math.h>

#define BATCH 64
#define TLEN 512
#define EMB 256
#define HID 256          // per-direction hidden
#define G4 1024          // 4*HID
#define KTAG 12
#define START_TAG 10
#define STOP_TAG 11
#define NEGV -10000.0f

#define LOG2E 1.4426950408889634f

__device__ __forceinline__ float fsig(float x) {
    // 1/(1+e^-x) via hw exp2+rcp; saturates correctly at +-inf
    return __builtin_amdgcn_rcpf(1.f + __builtin_amdgcn_exp2f(-LOG2E * x));
}
__device__ __forceinline__ float ftanh(float x) {
    // 1 - 2/(e^{2x}+1)
    return 1.f - 2.f * __builtin_amdgcn_rcpf(1.f + __builtin_amdgcn_exp2f(2.f * LOG2E * x));
}
__device__ __forceinline__ float ld_llc(const float* p) {
    return __hip_atomic_load(p, __ATOMIC_RELAXED, __HIP_MEMORY_SCOPE_AGENT);
}
__device__ __forceinline__ void st_llc(float* p, float v) {
    __hip_atomic_store(p, v, __ATOMIC_RELAXED, __HIP_MEMORY_SCOPE_AGENT);
}
__device__ __forceinline__ unsigned ld_llc_u(const unsigned* p) {
    return __hip_atomic_load(p, __ATOMIC_RELAXED, __HIP_MEMORY_SCOPE_AGENT);
}
__device__ __forceinline__ void st_llc_u(unsigned* p, unsigned v) {
    __hip_atomic_store(p, v, __ATOMIC_RELAXED, __HIP_MEMORY_SCOPE_AGENT);
}

// ---------------------------------------------------------------------------
// K1: fused embedding gather + input projection, both directions.
// OUTPUT LAYOUT CHANGE: column = j*4 + gate  (gates interleaved) so the scan
// kernel reads its 4 gate pre-acts as ONE float4.
// ---------------------------------------------------------------------------
#define MT 128
#define NT 128
#define KC 32
#define LDP 132

__global__ __launch_bounds__(256) void proj_kernel(
    const int* __restrict__ sentence, const float* __restrict__ emb,
    const float* __restrict__ Wf_ih, const float* __restrict__ Wb_ih,
    const float* __restrict__ bf_ih, const float* __restrict__ bf_hh,
    const float* __restrict__ bb_ih, const float* __restrict__ bb_hh,
    float* __restrict__ xf, float* __restrict__ xb) {
    int mtile = blockIdx.x;
    int ntile = blockIdx.y;
    int tid = threadIdx.x;

    __shared__ float As[KC][LDP];
    __shared__ float Bs[KC][LDP];
    __shared__ int tok[MT];

    int g2base = ntile * NT;
    const bool fwd = (g2base < 1024);
    const float* Wih = fwd ? Wf_ih : Wb_ih;
    const float* bia = fwd ? bf_ih : bb_ih;
    const float* bib = fwd ? bf_hh : bb_hh;
    float* dst       = fwd ? xf    : xb;
    int glb = g2base & 1023;

    if (tid < MT) tok[tid] = sentence[(size_t)mtile * MT + tid];
    __syncthreads();

    float acc[8][8];
#pragma unroll
    for (int i = 0; i < 8; ++i)
#pragma unroll
        for (int jj = 0; jj < 8; ++jj) acc[i][jj] = 0.f;

    int m0 = (tid & 15) * 8;
    int n0 = (tid >> 4) * 8;
    int lr = tid >> 3;
    int lk = (tid & 7) * 4;

    for (int k0 = 0; k0 < EMB; k0 += KC) {
#pragma unroll
        for (int i = 0; i < 4; ++i) {
            int r = lr + 32 * i;
            float4 v = *(const float4*)(emb + (size_t)tok[r] * EMB + k0 + lk);
            As[lk + 0][r] = v.x; As[lk + 1][r] = v.y;
            As[lk + 2][r] = v.z; As[lk + 3][r] = v.w;
            float4 w = *(const float4*)(Wih + (size_t)(glb + r) * EMB + k0 + lk);
            Bs[lk + 0][r] = w.x; Bs[lk + 1][r] = w.y;
            Bs[lk + 2][r] = w.z; Bs[lk + 3][r] = w.w;
        }
        __syncthreads();
#pragma unroll
        for (int kk = 0; kk < KC; ++kk) {
            float4 a0 = *(const float4*)&As[kk][m0];
            float4 a1 = *(const float4*)&As[kk][m0 + 4];
            float4 b0 = *(const float4*)&Bs[kk][n0];
            float4 b1 = *(const float4*)&Bs[kk][n0 + 4];
            float av[8] = {a0.x, a0.y, a0.z, a0.w, a1.x, a1.y, a1.z, a1.w};
            float bv[8] = {b0.x, b0.y, b0.z, b0.w, b1.x, b1.y, b1.z, b1.w};
#pragma unroll
            for (int i = 0; i < 8; ++i)
#pragma unroll
                for (int jj = 0; jj < 8; ++jj) acc[i][jj] += av[i] * bv[jj];
        }
        __syncthreads();
    }

#pragma unroll
    for (int jj = 0; jj < 8; ++jj) {
        int gl = glb + n0 + jj;                    // row in [0,1024): gate*256+j
        float bias = bia[gl] + bib[gl];
        int col = (gl & 255) * 4 + (gl >> 8);      // -> j*4+gate
#pragma unroll
        for (int i = 0; i < 8; ++i) {
            size_t r = (size_t)mtile * MT + m0 + i;
            dst[r * (size_t)G4 + col] = acc[i][jj] + bias;
        }
    }
}

// ---------------------------------------------------------------------------
// K2: cooperative LSTM scan, fence-free LLC sync.
// 256 blocks = 16 groups (2 dir x 8 batch-octets) x 16 J-slices.
// Thread map: tid = rp*16 + kseg; rp in [0,16) -> J = s*16+rp; kseg in [0,16).
// Per thread W: 4 gate-rows of J, k in {64q + 4*kseg + e} (swizzled for
// 2-way-free LDS banks). 16 B h-read feeds 16 FMAs. Reduce over kseg via
// DPP shfl_xor(1,2,4,8). Owner lane (bb == kseg&7) captures its gate quad;
// activations once per lane after the bb loop.
// Sync: h published via relaxed agent atomics (LLC-coherent, no fences);
// per-block arrival slot written after __syncthreads' vmcnt(0) drain;
// 16 lanes poll the group's 16-slot line with one coalesced load/iter.
// ---------------------------------------------------------------------------
__global__ __launch_bounds__(256) void lstm_scan3(
    const float* __restrict__ xf, const float* __restrict__ xb,
    const float* __restrict__ Wf_hh, const float* __restrict__ Wb_hh,
    float* __restrict__ hglob,          // [16 grp][2 slot][8 bb][256]
    unsigned* __restrict__ arrive,      // [16 grp][16 slice]
    float* __restrict__ hcat) {
    int blk = blockIdx.x;
    int grp = blk & 15;          // d*8+g  (members share blk%8: XCD heuristic)
    int s   = blk >> 4;          // J-slice 0..15
    int d   = grp >> 3;
    int g   = grp & 7;
    int tid = threadIdx.x;
    int kseg = tid & 15;
    int rp   = tid >> 4;
    int J    = s * 16 + rp;
    int bown = kseg & 7;
    int b0   = g * 8;

    // --- W: 4 gate-rows of J, swizzled 16-wide k-slice -> 64 VGPRs ---
    const float* Whh = d ? Wb_hh : Wf_hh;
    float4 Wr[4][4];
#pragma unroll
    for (int g4 = 0; g4 < 4; ++g4)
#pragma unroll
        for (int q = 0; q < 4; ++q)
            Wr[g4][q] = *(const float4*)(Whh + (size_t)(g4 * 256 + J) * 256 + q * 64 + kseg * 4);

    const float* xbase = (d ? xb : xf) + (size_t)(b0 + bown) * TLEN * G4;
    float* hbuf = hglob + (size_t)grp * 4096;     // 2 slots x 2048 floats
    unsigned* arr = arrive + grp * 16;

    __shared__ float hsL[2048];   // [bb][256]
    float c = 0.f;

    for (int i = 0; i < TLEN; ++i) {
        int t = d ? (TLEN - 1 - i) : i;

        // prefetch own x gate-quad (independent of peers)
        float4 xv = *(const float4*)(xbase + (size_t)t * G4 + J * 4);

        if (i == 0) {
#pragma unroll
            for (int bb = 0; bb < 8; ++bb) hsL[bb * 256 + tid] = 0.f;
        } else {
            if (tid < 64) {                       // wave 0 polls
                unsigned tgt = (unsigned)i;
                for (;;) {
                    unsigned v = (tid < 16) ? ld_llc_u(arr + tid) : 0xffffffffu;
                    if (__ballot(v >= tgt) == ~0ull) break;
                    __builtin_amdgcn_s_sleep(2);
                }
            }
            __syncthreads();
            const float* src = hbuf + ((i - 1) & 1) * 2048;
#pragma unroll
            for (int bb = 0; bb < 8; ++bb)
                hsL[bb * 256 + tid] = ld_llc(src + bb * 256 + tid);
        }
        __syncthreads();

        float4 own = {0.f, 0.f, 0.f, 0.f};
#pragma unroll
        for (int bb = 0; bb < 8; ++bb) {
            float a0 = 0.f, a1 = 0.f, a2 = 0.f, a3 = 0.f;
            const float* hb = hsL + bb * 256 + kseg * 4;
#pragma unroll
            for (int q = 0; q < 4; ++q) {
                float4 h4 = *(const float4*)(hb + q * 64);
                float4 w;
                w = Wr[0][q]; a0 += w.x*h4.x + w.y*h4.y + w.z*h4.z + w.w*h4.w;
                w = Wr[1][q]; a1 += w.x*h4.x + w.y*h4.y + w.z*h4.z + w.w*h4.w;
                w = Wr[2][q]; a2 += w.x*h4.x + w.y*h4.y + w.z*h4.z + w.w*h4.w;
                w = Wr[3][q]; a3 += w.x*h4.x + w.y*h4.y + w.z*h4.z + w.w*h4.w;
            }
#pragma unroll
            for (int m = 1; m <= 8; m <<= 1) {
                a0 += __shfl_xor(a0, m);
                a1 += __shfl_xor(a1, m);
                a2 += __shfl_xor(a2, m);
                a3 += __shfl_xor(a3, m);
            }
            bool ow = (bb == bown);
            own.x = ow ? a0 : own.x;
            own.y = ow ? a1 : own.y;
            own.z = ow ? a2 : own.z;
            own.w = ow ? a3 : own.w;
        }

        // activations once per lane, for (J, bown)
        float ig = fsig(own.x + xv.x);
        float fg = fsig(own.y + xv.y);
        float gg = ftanh(own.z + xv.z);
        float og = fsig(own.w + xv.w);
        c = fg * c + ig * gg;
        float h = og * ftanh(c);

        if (kseg < 8) {
            st_llc(hbuf + (i & 1) * 2048 + kseg * 256 + J, h);
            hcat[((size_t)t * BATCH + b0 + kseg) * 512 + (size_t)d * HID + J] = h;
        }

        __syncthreads();                   // drains vmcnt(0): h stores at LLC
        if (tid == 0) st_llc_u(arr + s, (unsigned)(i + 1));
    }
}

// ---------------------------------------------------------------------------
// K3: feats[t,b,k] = hcat[t,b,:] . W_out[k,:] + b_out[k].
// ---------------------------------------------------------------------------
__global__ __launch_bounds__(256) void feats_kernel(
    const float* __restrict__ hcat, const float* __restrict__ Wout,
    const float* __restrict__ bout, float* __restrict__ feats) {
    int wid = threadIdx.x >> 6;
    int lane = threadIdx.x & 63;
    size_t row = (size_t)blockIdx.x * 4 + wid;
    const float* hrow = hcat + row * 512;
    float4 h0 = *(const float4*)(hrow + lane * 8);
    float4 h1 = *(const float4*)(hrow + lane * 8 + 4);
    for (int k2 = 0; k2 < KTAG; ++k2) {
        const float* wr = Wout + (size_t)k2 * 512 + lane * 8;
        float4 w0 = *(const float4*)wr;
        float4 w1 = *(const float4*)(wr + 4);
        float p = h0.x * w0.x + h0.y * w0.y + h0.z * w0.z + h0.w * w0.w
                + h1.x * w1.x + h1.y * w1.y + h1.z * w1.z + h1.w * w1.w;
#pragma unroll
        for (int off = 32; off; off >>= 1) p += __shfl_down(p, off);
        if (lane == 0) feats[row * KTAG + k2] = p + bout[k2];
    }
}

// ---------------------------------------------------------------------------
// K4: Viterbi DP + backtrace. One wave per batch. First-max tie-break.
// ---------------------------------------------------------------------------
__global__ __launch_bounds__(64) void viterbi_kernel(
    const float* __restrict__ feats, const float* __restrict__ trans,
    const int* __restrict__ slen, float* __restrict__ out) {
    int b = blockIdx.x;
    int lane = threadIdx.x;
    __shared__ unsigned char bp[TLEN][KTAG];

    int len = slen[b];
    float tr[KTAG];
#pragma unroll
    for (int p = 0; p < KTAG; ++p) tr[p] = 0.f;
    if (lane < KTAG) {
#pragma unroll
        for (int p = 0; p < KTAG; ++p) tr[p] = trans[lane * KTAG + p];
    }
    float tstop = (lane < KTAG) ? trans[STOP_TAG * KTAG + lane] : NEGV;
    float dp = (lane == START_TAG) ? 0.f : NEGV;

    float ftn = (lane < KTAG) ? feats[(size_t)b * KTAG + lane] : 0.f;
    for (int t = 0; t < TLEN; ++t) {
        float ftc = ftn;
        if (t + 1 < TLEN && lane < KTAG)
            ftn = feats[((size_t)(t + 1) * BATCH + b) * KTAG + lane];
        float best = -1e30f;
        int arg = 0;
#pragma unroll
        for (int p = 0; p < KTAG; ++p) {
            float dpp = __shfl(dp, p);
            float s = dpp + tr[p];
            if (s > best) { best = s; arg = p; }
        }
        bool m = (t < len);
        if (lane < KTAG) {
            dp = m ? (best + ftc) : dp;
            bp[t][lane] = (unsigned char)(m ? arg : lane);
        }
    }

    float term = dp + tstop;
    float bbest = -1e30f;
    int barg = 0;
#pragma unroll
    for (int p = 0; p < KTAG; ++p) {
        float v = __shfl(term, p);
        if (v > bbest) { bbest = v; barg = p; }
    }
    if (lane == 0) {
        out[b] = bbest;
        float* path = out + BATCH + (size_t)b * TLEN;
        int tag = barg;
        for (int t = TLEN - 1; t >= 0; --t) {
            path[t] = (float)tag;
            tag = bp[t][tag];
        }
    }
}

// ---------------------------------------------------------------------------
extern "C" void kernel_launch(void* const* d_in, const int* in_sizes, int n_in,
                              void* d_out, int out_size, void* d_ws, size_t ws_size,
                              hipStream_t stream) {
    const int*   sentence = (const int*)d_in[0];
    const int*   slen     = (const int*)d_in[1];
    const float* emb      = (const float*)d_in[2];
    const float* Wf_ih    = (const float*)d_in[3];
    const float* Wf_hh    = (const float*)d_in[4];
    const float* bf_ih    = (const float*)d_in[5];
    const float* bf_hh    = (const float*)d_in[6];
    const float* Wb_ih    = (const float*)d_in[7];
    const float* Wb_hh    = (const float*)d_in[8];
    const float* bb_ih    = (const float*)d_in[9];
    const float* bb_hh    = (const float*)d_in[10];
    const float* W_out    = (const float*)d_in[11];
    const float* b_out    = (const float*)d_in[12];
    const float* trans    = (const float*)d_in[13];
    float* out = (float*)d_out;

    char* ws = (char*)d_ws;
    float*    xf    = (float*)(ws);                       // 134,217,728 B
    float*    xb    = (float*)(ws + 134217728ull);        // 134,217,728 B
    float*    hcat  = (float*)(ws + 268435456ull);        //  67,108,864 B
    float*    feats = (float*)(ws + 335544320ull);        //   1,572,864 B
    float*    hglob = (float*)(ws + 337117184ull);        //     262,144 B
    unsigned* arrive = (unsigned*)(ws + 337379328ull);    //       1,024 B

    hipMemsetAsync(arrive, 0, 16 * 16 * sizeof(unsigned), stream);
    hipLaunchKernelGGL(proj_kernel, dim3(256, 16), dim3(256), 0, stream,
                       sentence, emb, Wf_ih, Wb_ih, bf_ih, bf_hh, bb_ih, bb_hh, xf, xb);
    hipLaunchKernelGGL(lstm_scan3, dim3(256), dim3(256), 0, stream,
                       xf, xb, Wf_hh, Wb_hh, hglob, arrive, hcat);
    hipLaunchKernelGGL(feats_kernel, dim3(8192), dim3(256), 0, stream,
                       hcat, W_out, b_out, feats);
    hipLaunchKernelGGL(viterbi_kernel, dim3(64), dim3(64), 0, stream,
                       feats, trans, slen, out);
}

// Round 4
// 3304.815 us; speedup vs baseline: 3.7800x; 1.2665x over previous
//
#include <hip/hip_runtime.h>
#include <math.h>

#define BATCH 64
#define TLEN 512
#define EMB 256
#define HID 256          // per-direction hidden
#define G4 1024          // 4*HID
#define KTAG 12
#define START_TAG 10
#define STOP_TAG 11
#define NEGV -10000.0f
#define SENT 0xFFFFFFFFu // -NaN sentinel: tanh-bounded h can never be this

#define LOG2E 1.4426950408889634f

__device__ __forceinline__ float fsig(float x) {
    return __builtin_amdgcn_rcpf(1.f + __builtin_amdgcn_exp2f(-LOG2E * x));
}
__device__ __forceinline__ float ftanh(float x) {
    return 1.f - 2.f * __builtin_amdgcn_rcpf(1.f + __builtin_amdgcn_exp2f(2.f * LOG2E * x));
}
__device__ __forceinline__ void st_llc(float* p, float v) {
    __hip_atomic_store(p, v, __ATOMIC_RELAXED, __HIP_MEMORY_SCOPE_AGENT);
}
__device__ __forceinline__ unsigned ld_llc_u(const unsigned* p) {
    return __hip_atomic_load(p, __ATOMIC_RELAXED, __HIP_MEMORY_SCOPE_AGENT);
}

// ---------------------------------------------------------------------------
// K1: fused embedding gather + input projection, both directions.
// Round-1 x layout: x[r][gate*256+j], r = b*512+t. float4 epilogue stores.
// ---------------------------------------------------------------------------
#define MT 128
#define NT 128
#define KC 32
#define LDP 132

__global__ __launch_bounds__(256) void proj_kernel(
    const int* __restrict__ sentence, const float* __restrict__ emb,
    const float* __restrict__ Wf_ih, const float* __restrict__ Wb_ih,
    const float* __restrict__ bf_ih, const float* __restrict__ bf_hh,
    const float* __restrict__ bb_ih, const float* __restrict__ bb_hh,
    float* __restrict__ xf, float* __restrict__ xb) {
    int mtile = blockIdx.x;
    int ntile = blockIdx.y;
    int tid = threadIdx.x;

    __shared__ float As[KC][LDP];
    __shared__ float Bs[KC][LDP];
    __shared__ int tok[MT];

    int g2base = ntile * NT;
    const bool fwd = (g2base < 1024);
    const float* Wih = fwd ? Wf_ih : Wb_ih;
    const float* bia = fwd ? bf_ih : bb_ih;
    const float* bib = fwd ? bf_hh : bb_hh;
    float* dst       = fwd ? xf    : xb;
    int glb = g2base & 1023;

    if (tid < MT) tok[tid] = sentence[(size_t)mtile * MT + tid];
    __syncthreads();

    float acc[8][8];
#pragma unroll
    for (int i = 0; i < 8; ++i)
#pragma unroll
        for (int jj = 0; jj < 8; ++jj) acc[i][jj] = 0.f;

    int m0 = (tid & 15) * 8;
    int n0 = (tid >> 4) * 8;
    int lr = tid >> 3;
    int lk = (tid & 7) * 4;

    for (int k0 = 0; k0 < EMB; k0 += KC) {
#pragma unroll
        for (int i = 0; i < 4; ++i) {
            int r = lr + 32 * i;
            float4 v = *(const float4*)(emb + (size_t)tok[r] * EMB + k0 + lk);
            As[lk + 0][r] = v.x; As[lk + 1][r] = v.y;
            As[lk + 2][r] = v.z; As[lk + 3][r] = v.w;
            float4 w = *(const float4*)(Wih + (size_t)(glb + r) * EMB + k0 + lk);
            Bs[lk + 0][r] = w.x; Bs[lk + 1][r] = w.y;
            Bs[lk + 2][r] = w.z; Bs[lk + 3][r] = w.w;
        }
        __syncthreads();
#pragma unroll
        for (int kk = 0; kk < KC; ++kk) {
            float4 a0 = *(const float4*)&As[kk][m0];
            float4 a1 = *(const float4*)&As[kk][m0 + 4];
            float4 b0 = *(const float4*)&Bs[kk][n0];
            float4 b1 = *(const float4*)&Bs[kk][n0 + 4];
            float av[8] = {a0.x, a0.y, a0.z, a0.w, a1.x, a1.y, a1.z, a1.w};
            float bv[8] = {b0.x, b0.y, b0.z, b0.w, b1.x, b1.y, b1.z, b1.w};
#pragma unroll
            for (int i = 0; i < 8; ++i)
#pragma unroll
                for (int jj = 0; jj < 8; ++jj) acc[i][jj] += av[i] * bv[jj];
        }
        __syncthreads();
    }

    float bs[8];
#pragma unroll
    for (int jj = 0; jj < 8; ++jj) {
        int gl = glb + n0 + jj;
        bs[jj] = bia[gl] + bib[gl];
    }
#pragma unroll
    for (int i = 0; i < 8; ++i) {
        size_t r = (size_t)mtile * MT + m0 + i;
        float4 s0 = {acc[i][0] + bs[0], acc[i][1] + bs[1],
                     acc[i][2] + bs[2], acc[i][3] + bs[3]};
        float4 s1 = {acc[i][4] + bs[4], acc[i][5] + bs[5],
                     acc[i][6] + bs[6], acc[i][7] + bs[7]};
        *(float4*)(dst + r * (size_t)G4 + glb + n0)     = s0;
        *(float4*)(dst + r * (size_t)G4 + glb + n0 + 4) = s1;
    }
}

// ---------------------------------------------------------------------------
// K2: cooperative LSTM scan v4 — data-is-the-flag through hcat.
// 256 blocks = 32 groups (2 dir x 16 batch-quartets) x 8 J-slice blocks.
// Thread map: tid = j*8 + kseg; j in [0,32) -> J = s*32+j; kseg in [0,8)
// owns k-chunk [kseg*32, kseg*32+32). W/thread = 4 gates x 32 k = 128 VGPRs.
// Producers: relaxed agent stores of h straight into hcat[t] (fire & forget,
// no flag, no drain — hcat slot per t is write-once). Consumers: each thread
// polls exactly the 4 words it stages (4 bb x J=tid), all 4 loads issued per
// poll iteration; sentinel 0xFFFFFFFF set by a per-launch memset.
// LDS h staging k-swizzled in 36-float chunks: conflict-free b128 broadcast.
// ---------------------------------------------------------------------------
__global__ __launch_bounds__(256) void lstm_scan4(
    const float* __restrict__ xf, const float* __restrict__ xb,
    const float* __restrict__ Wf_hh, const float* __restrict__ Wb_hh,
    float* __restrict__ hcat) {
    int blk = blockIdx.x;
    int grp = blk & 31;          // members of a group share blk%8 (XCD heur.)
    int s   = blk >> 5;          // J-slice 0..7
    int d   = grp >> 4;          // direction
    int gq  = grp & 15;          // batch quartet
    int b0  = gq * 4;
    int tid = threadIdx.x;
    int kseg = tid & 7;
    int j    = tid >> 3;
    int J    = s * 32 + j;
    int bown = kseg & 3;

    // --- W: 4 gate-rows of J, k-slice [kseg*32, +32) -> 128 VGPRs ---
    const float* Whh = d ? Wb_hh : Wf_hh;
    float4 Wr[4][8];
#pragma unroll
    for (int g = 0; g < 4; ++g)
#pragma unroll
        for (int q = 0; q < 8; ++q)
            Wr[g][q] = *(const float4*)(Whh + (size_t)(g * 256 + J) * 256 + kseg * 32 + q * 4);

    const float* x = d ? xb : xf;
    const float* xrow0 = x + (size_t)(b0 + bown) * TLEN * G4 + J;

    __shared__ float hsL[4 * 288];   // [bb][8 chunks x 36] swizzled
    int sw = (tid >> 5) * 36 + (tid & 31);
    float c = 0.f;

    for (int i = 0; i < TLEN; ++i) {
        int t = d ? (TLEN - 1 - i) : i;

        // prefetch own x gate pre-acts (independent of peers)
        const float* xr = xrow0 + (size_t)t * G4;
        float x0 = xr[0], x1 = xr[256], x2 = xr[512], x3 = xr[768];

        if (i == 0) {
#pragma unroll
            for (int bb = 0; bb < 4; ++bb) hsL[bb * 288 + sw] = 0.f;
        } else {
            int tp = d ? (t + 1) : (t - 1);
            const unsigned* base = (const unsigned*)hcat +
                ((size_t)tp * BATCH + b0) * 512 + (size_t)d * HID + tid;
            unsigned u0, u1, u2, u3;
            for (;;) {
                u0 = ld_llc_u(base);
                u1 = ld_llc_u(base + 512);
                u2 = ld_llc_u(base + 1024);
                u3 = ld_llc_u(base + 1536);
                if (u0 != SENT && u1 != SENT && u2 != SENT && u3 != SENT) break;
                __builtin_amdgcn_s_sleep(1);
            }
            hsL[0 * 288 + sw] = __uint_as_float(u0);
            hsL[1 * 288 + sw] = __uint_as_float(u1);
            hsL[2 * 288 + sw] = __uint_as_float(u2);
            hsL[3 * 288 + sw] = __uint_as_float(u3);
        }
        __syncthreads();

        float ox = 0.f, oy = 0.f, oz = 0.f, ow_ = 0.f;
#pragma unroll
        for (int bb = 0; bb < 4; ++bb) {
            const float* hb = hsL + bb * 288 + kseg * 36;
            float a0 = 0.f, a1 = 0.f, a2 = 0.f, a3 = 0.f;
#pragma unroll
            for (int q = 0; q < 8; ++q) {
                float4 h4 = *(const float4*)(hb + q * 4);
                float4 w;
                w = Wr[0][q]; a0 += w.x*h4.x + w.y*h4.y + w.z*h4.z + w.w*h4.w;
                w = Wr[1][q]; a1 += w.x*h4.x + w.y*h4.y + w.z*h4.z + w.w*h4.w;
                w = Wr[2][q]; a2 += w.x*h4.x + w.y*h4.y + w.z*h4.z + w.w*h4.w;
                w = Wr[3][q]; a3 += w.x*h4.x + w.y*h4.y + w.z*h4.z + w.w*h4.w;
            }
#pragma unroll
            for (int m = 1; m <= 4; m <<= 1) {
                a0 += __shfl_xor(a0, m);
                a1 += __shfl_xor(a1, m);
                a2 += __shfl_xor(a2, m);
                a3 += __shfl_xor(a3, m);
            }
            bool own = (bb == bown);
            ox  = own ? a0 : ox;
            oy  = own ? a1 : oy;
            oz  = own ? a2 : oz;
            ow_ = own ? a3 : ow_;
        }
        __syncthreads();     // compute reads of hsL done before next restage

        // activations for (J, b0+bown); kseg and kseg+4 compute identically
        float ig = fsig(ox + x0);
        float fg = fsig(oy + x1);
        float gg = ftanh(oz + x2);
        float og = fsig(ow_ + x3);
        c = fg * c + ig * gg;
        float h = og * ftanh(c);

        if (kseg < 4)
            st_llc(hcat + ((size_t)t * BATCH + b0 + bown) * 512 + (size_t)d * HID + J, h);
    }
}

// ---------------------------------------------------------------------------
// K3: feats[t,b,k] = hcat[t,b,:] . W_out[k,:] + b_out[k].
// ---------------------------------------------------------------------------
__global__ __launch_bounds__(256) void feats_kernel(
    const float* __restrict__ hcat, const float* __restrict__ Wout,
    const float* __restrict__ bout, float* __restrict__ feats) {
    int wid = threadIdx.x >> 6;
    int lane = threadIdx.x & 63;
    size_t row = (size_t)blockIdx.x * 4 + wid;
    const float* hrow = hcat + row * 512;
    float4 h0 = *(const float4*)(hrow + lane * 8);
    float4 h1 = *(const float4*)(hrow + lane * 8 + 4);
    for (int k2 = 0; k2 < KTAG; ++k2) {
        const float* wr = Wout + (size_t)k2 * 512 + lane * 8;
        float4 w0 = *(const float4*)wr;
        float4 w1 = *(const float4*)(wr + 4);
        float p = h0.x * w0.x + h0.y * w0.y + h0.z * w0.z + h0.w * w0.w
                + h1.x * w1.x + h1.y * w1.y + h1.z * w1.z + h1.w * w1.w;
#pragma unroll
        for (int off = 32; off; off >>= 1) p += __shfl_down(p, off);
        if (lane == 0) feats[row * KTAG + k2] = p + bout[k2];
    }
}

// ---------------------------------------------------------------------------
// K4: Viterbi DP + backtrace. One wave per batch. 8-step feats prefetch ring
// hides the ~200-600 cyc L2 load latency that was unhidden at 1-step depth.
// ---------------------------------------------------------------------------
__global__ __launch_bounds__(64) void viterbi_kernel(
    const float* __restrict__ feats, const float* __restrict__ trans,
    const int* __restrict__ slen, float* __restrict__ out) {
    int b = blockIdx.x;
    int lane = threadIdx.x;
    __shared__ unsigned char bp[TLEN][KTAG];

    int len = slen[b];
    float tr[KTAG];
#pragma unroll
    for (int p = 0; p < KTAG; ++p) tr[p] = 0.f;
    if (lane < KTAG) {
#pragma unroll
        for (int p = 0; p < KTAG; ++p) tr[p] = trans[lane * KTAG + p];
    }
    float tstop = (lane < KTAG) ? trans[STOP_TAG * KTAG + lane] : NEGV;
    float dp = (lane == START_TAG) ? 0.f : NEGV;

    float fb[8];
#pragma unroll
    for (int k = 0; k < 8; ++k)
        fb[k] = (lane < KTAG) ? feats[((size_t)k * BATCH + b) * KTAG + lane] : 0.f;

    for (int t0 = 0; t0 < TLEN; t0 += 8) {
#pragma unroll
        for (int u = 0; u < 8; ++u) {
            int t = t0 + u;
            float ftc = fb[u];
            int tn = t + 8;
            fb[u] = (tn < TLEN && lane < KTAG)
                        ? feats[((size_t)tn * BATCH + b) * KTAG + lane] : 0.f;
            float best = -1e30f;
            int arg = 0;
#pragma unroll
            for (int p = 0; p < KTAG; ++p) {
                float dpp = __shfl(dp, p);
                float sc = dpp + tr[p];
                if (sc > best) { best = sc; arg = p; }
            }
            bool m = (t < len);
            if (lane < KTAG) {
                dp = m ? (best + ftc) : dp;
                bp[t][lane] = (unsigned char)(m ? arg : lane);
            }
        }
    }

    float term = dp + tstop;
    float bbest = -1e30f;
    int barg = 0;
#pragma unroll
    for (int p = 0; p < KTAG; ++p) {
        float v = __shfl(term, p);
        if (v > bbest) { bbest = v; barg = p; }
    }
    if (lane == 0) {
        out[b] = bbest;
        float* path = out + BATCH + (size_t)b * TLEN;
        int tag = barg;
        for (int t = TLEN - 1; t >= 0; --t) {
            path[t] = (float)tag;
            tag = bp[t][tag];
        }
    }
}

// ---------------------------------------------------------------------------
extern "C" void kernel_launch(void* const* d_in, const int* in_sizes, int n_in,
                              void* d_out, int out_size, void* d_ws, size_t ws_size,
                              hipStream_t stream) {
    const int*   sentence = (const int*)d_in[0];
    const int*   slen     = (const int*)d_in[1];
    const float* emb      = (const float*)d_in[2];
    const float* Wf_ih    = (const float*)d_in[3];
    const float* Wf_hh    = (const float*)d_in[4];
    const float* bf_ih    = (const float*)d_in[5];
    const float* bf_hh    = (const float*)d_in[6];
    const float* Wb_ih    = (const float*)d_in[7];
    const float* Wb_hh    = (const float*)d_in[8];
    const float* bb_ih    = (const float*)d_in[9];
    const float* bb_hh    = (const float*)d_in[10];
    const float* W_out    = (const float*)d_in[11];
    const float* b_out    = (const float*)d_in[12];
    const float* trans    = (const float*)d_in[13];
    float* out = (float*)d_out;

    char* ws = (char*)d_ws;
    float* xf    = (float*)(ws);                       // 134,217,728 B
    float* xb    = (float*)(ws + 134217728ull);        // 134,217,728 B
    float* hcat  = (float*)(ws + 268435456ull);        //  67,108,864 B
    float* feats = (float*)(ws + 335544320ull);        //   1,572,864 B

    // sentinel-fill hcat: 0xFFFFFFFF = -NaN, unreachable for tanh-bounded h
    hipMemsetAsync(hcat, 0xFF, 67108864ull, stream);
    hipLaunchKernelGGL(proj_kernel, dim3(256, 16), dim3(256), 0, stream,
                       sentence, emb, Wf_ih, Wb_ih, bf_ih, bf_hh, bb_ih, bb_hh, xf, xb);
    hipLaunchKernelGGL(lstm_scan4, dim3(256), dim3(256), 0, stream,
                       xf, xb, Wf_hh, Wb_hh, hcat);
    hipLaunchKernelGGL(feats_kernel, dim3(8192), dim3(256), 0, stream,
                       hcat, W_out, b_out, feats);
    hipLaunchKernelGGL(viterbi_kernel, dim3(64), dim3(64), 0, stream,
                       feats, trans, slen, out);
}

// Round 5
// 2363.635 us; speedup vs baseline: 5.2852x; 1.3982x over previous
//
#include <hip/hip_runtime.h>
#include <math.h>

#define BATCH 64
#define TLEN 512
#define EMB 256
#define HID 256          // per-direction hidden
#define G4 1024          // 4*HID
#define KTAG 12
#define START_TAG 10
#define STOP_TAG 11
#define NEGV -10000.0f
#define SENT 0xFFFFFFFFu // -NaN sentinel: tanh-bounded h can never be this

#define LOG2E 1.4426950408889634f

__device__ __forceinline__ float fsig(float x) {
    return __builtin_amdgcn_rcpf(1.f + __builtin_amdgcn_exp2f(-LOG2E * x));
}
__device__ __forceinline__ float ftanh(float x) {
    return 1.f - 2.f * __builtin_amdgcn_rcpf(1.f + __builtin_amdgcn_exp2f(2.f * LOG2E * x));
}
__device__ __forceinline__ void st_llc(float* p, float v) {
    __hip_atomic_store(p, v, __ATOMIC_RELAXED, __HIP_MEMORY_SCOPE_AGENT);
}
__device__ __forceinline__ unsigned ld_llc_u(const unsigned* p) {
    return __hip_atomic_load(p, __ATOMIC_RELAXED, __HIP_MEMORY_SCOPE_AGENT);
}

// ---------------------------------------------------------------------------
// K1: fused embedding gather + input projection, both directions.
// x layout: x[r][gate*256+j], r = b*512+t. float4 epilogue stores.
// ---------------------------------------------------------------------------
#define MT 128
#define NT 128
#define KC 32
#define LDP 132

__global__ __launch_bounds__(256) void proj_kernel(
    const int* __restrict__ sentence, const float* __restrict__ emb,
    const float* __restrict__ Wf_ih, const float* __restrict__ Wb_ih,
    const float* __restrict__ bf_ih, const float* __restrict__ bf_hh,
    const float* __restrict__ bb_ih, const float* __restrict__ bb_hh,
    float* __restrict__ xf, float* __restrict__ xb) {
    int mtile = blockIdx.x;
    int ntile = blockIdx.y;
    int tid = threadIdx.x;

    __shared__ float As[KC][LDP];
    __shared__ float Bs[KC][LDP];
    __shared__ int tok[MT];

    int g2base = ntile * NT;
    const bool fwd = (g2base < 1024);
    const float* Wih = fwd ? Wf_ih : Wb_ih;
    const float* bia = fwd ? bf_ih : bb_ih;
    const float* bib = fwd ? bf_hh : bb_hh;
    float* dst       = fwd ? xf    : xb;
    int glb = g2base & 1023;

    if (tid < MT) tok[tid] = sentence[(size_t)mtile * MT + tid];
    __syncthreads();

    float acc[8][8];
#pragma unroll
    for (int i = 0; i < 8; ++i)
#pragma unroll
        for (int jj = 0; jj < 8; ++jj) acc[i][jj] = 0.f;

    int m0 = (tid & 15) * 8;
    int n0 = (tid >> 4) * 8;
    int lr = tid >> 3;
    int lk = (tid & 7) * 4;

    for (int k0 = 0; k0 < EMB; k0 += KC) {
#pragma unroll
        for (int i = 0; i < 4; ++i) {
            int r = lr + 32 * i;
            float4 v = *(const float4*)(emb + (size_t)tok[r] * EMB + k0 + lk);
            As[lk + 0][r] = v.x; As[lk + 1][r] = v.y;
            As[lk + 2][r] = v.z; As[lk + 3][r] = v.w;
            float4 w = *(const float4*)(Wih + (size_t)(glb + r) * EMB + k0 + lk);
            Bs[lk + 0][r] = w.x; Bs[lk + 1][r] = w.y;
            Bs[lk + 2][r] = w.z; Bs[lk + 3][r] = w.w;
        }
        __syncthreads();
#pragma unroll
        for (int kk = 0; kk < KC; ++kk) {
            float4 a0 = *(const float4*)&As[kk][m0];
            float4 a1 = *(const float4*)&As[kk][m0 + 4];
            float4 b0 = *(const float4*)&Bs[kk][n0];
            float4 b1 = *(const float4*)&Bs[kk][n0 + 4];
            float av[8] = {a0.x, a0.y, a0.z, a0.w, a1.x, a1.y, a1.z, a1.w};
            float bv[8] = {b0.x, b0.y, b0.z, b0.w, b1.x, b1.y, b1.z, b1.w};
#pragma unroll
            for (int i = 0; i < 8; ++i)
#pragma unroll
                for (int jj = 0; jj < 8; ++jj) acc[i][jj] += av[i] * bv[jj];
        }
        __syncthreads();
    }

    float bs[8];
#pragma unroll
    for (int jj = 0; jj < 8; ++jj) {
        int gl = glb + n0 + jj;
        bs[jj] = bia[gl] + bib[gl];
    }
#pragma unroll
    for (int i = 0; i < 8; ++i) {
        size_t r = (size_t)mtile * MT + m0 + i;
        float4 s0 = {acc[i][0] + bs[0], acc[i][1] + bs[1],
                     acc[i][2] + bs[2], acc[i][3] + bs[3]};
        float4 s1 = {acc[i][4] + bs[4], acc[i][5] + bs[5],
                     acc[i][6] + bs[6], acc[i][7] + bs[7]};
        *(float4*)(dst + r * (size_t)G4 + glb + n0)     = s0;
        *(float4*)(dst + r * (size_t)G4 + glb + n0 + 4) = s1;
    }
}

// ---------------------------------------------------------------------------
// K2: cooperative LSTM scan v5.
// Identical structure to v4 (data-is-the-flag via hcat sentinels) with:
//  (a) __launch_bounds__(256, 1): lifts the VGPR cap so Wr[4][8] (128 floats)
//      is truly register-resident — v4's VGPR_Count=84 proved the compiler
//      was re-streaming W every step (~1.1 us/step of per-CU L2 BW).
//  (b) owner lanes compute activations + publish h INSIDE the bb loop, so
//      h(bb) becomes LLC-visible as soon as its reduction completes.
// ---------------------------------------------------------------------------
__global__ __launch_bounds__(256, 1) void lstm_scan5(
    const float* __restrict__ xf, const float* __restrict__ xb,
    const float* __restrict__ Wf_hh, const float* __restrict__ Wb_hh,
    float* __restrict__ hcat) {
    int blk = blockIdx.x;
    int grp = blk & 31;          // members of a group share blk%8 (XCD heur.)
    int s   = blk >> 5;          // J-slice 0..7
    int d   = grp >> 4;          // direction
    int gq  = grp & 15;          // batch quartet
    int b0  = gq * 4;
    int tid = threadIdx.x;
    int kseg = tid & 7;
    int j    = tid >> 3;
    int J    = s * 32 + j;
    int bown = kseg & 3;

    // --- W: 4 gate-rows of J, k-slice [kseg*32, +32) -> 128 VGPRs ---
    const float* Whh = d ? Wb_hh : Wf_hh;
    float4 Wr[4][8];
#pragma unroll
    for (int g = 0; g < 4; ++g)
#pragma unroll
        for (int q = 0; q < 8; ++q)
            Wr[g][q] = *(const float4*)(Whh + (size_t)(g * 256 + J) * 256 + kseg * 32 + q * 4);

    const float* x = d ? xb : xf;
    const float* xrow0 = x + (size_t)(b0 + bown) * TLEN * G4 + J;

    __shared__ float hsL[4 * 288];   // [bb][8 chunks x 36] swizzled
    int sw = (tid >> 5) * 36 + (tid & 31);
    float c = 0.f;

    for (int i = 0; i < TLEN; ++i) {
        int t = d ? (TLEN - 1 - i) : i;

        // prefetch own x gate pre-acts (independent of peers)
        const float* xr = xrow0 + (size_t)t * G4;
        float x0 = xr[0], x1 = xr[256], x2 = xr[512], x3 = xr[768];

        if (i == 0) {
#pragma unroll
            for (int bb = 0; bb < 4; ++bb) hsL[bb * 288 + sw] = 0.f;
        } else {
            int tp = d ? (t + 1) : (t - 1);
            const unsigned* base = (const unsigned*)hcat +
                ((size_t)tp * BATCH + b0) * 512 + (size_t)d * HID + tid;
            unsigned u0, u1, u2, u3;
            for (;;) {
                u0 = ld_llc_u(base);
                u1 = ld_llc_u(base + 512);
                u2 = ld_llc_u(base + 1024);
                u3 = ld_llc_u(base + 1536);
                if (u0 != SENT && u1 != SENT && u2 != SENT && u3 != SENT) break;
                __builtin_amdgcn_s_sleep(1);
            }
            hsL[0 * 288 + sw] = __uint_as_float(u0);
            hsL[1 * 288 + sw] = __uint_as_float(u1);
            hsL[2 * 288 + sw] = __uint_as_float(u2);
            hsL[3 * 288 + sw] = __uint_as_float(u3);
        }
        __syncthreads();

#pragma unroll
        for (int bb = 0; bb < 4; ++bb) {
            const float* hb = hsL + bb * 288 + kseg * 36;
            float a0 = 0.f, a1 = 0.f, a2 = 0.f, a3 = 0.f;
#pragma unroll
            for (int q = 0; q < 8; ++q) {
                float4 h4 = *(const float4*)(hb + q * 4);
                float4 w;
                w = Wr[0][q]; a0 += w.x*h4.x + w.y*h4.y + w.z*h4.z + w.w*h4.w;
                w = Wr[1][q]; a1 += w.x*h4.x + w.y*h4.y + w.z*h4.z + w.w*h4.w;
                w = Wr[2][q]; a2 += w.x*h4.x + w.y*h4.y + w.z*h4.z + w.w*h4.w;
                w = Wr[3][q]; a3 += w.x*h4.x + w.y*h4.y + w.z*h4.z + w.w*h4.w;
            }
#pragma unroll
            for (int m = 1; m <= 4; m <<= 1) {
                a0 += __shfl_xor(a0, m);
                a1 += __shfl_xor(a1, m);
                a2 += __shfl_xor(a2, m);
                a3 += __shfl_xor(a3, m);
            }
            // owner lanes finish this batch NOW and publish h immediately
            if (bb == bown) {
                float ig = fsig(a0 + x0);
                float fg = fsig(a1 + x1);
                float gg = ftanh(a2 + x2);
                float og = fsig(a3 + x3);
                c = fg * c + ig * gg;
                float h = og * ftanh(c);
                if (kseg < 4)
                    st_llc(hcat + ((size_t)t * BATCH + b0 + bown) * 512
                                + (size_t)d * HID + J, h);
            }
        }
        __syncthreads();     // hsL reads done before next restage
    }
}

// ---------------------------------------------------------------------------
// K3: feats[t,b,k] = hcat[t,b,:] . W_out[k,:] + b_out[k].
// ---------------------------------------------------------------------------
__global__ __launch_bounds__(256) void feats_kernel(
    const float* __restrict__ hcat, const float* __restrict__ Wout,
    const float* __restrict__ bout, float* __restrict__ feats) {
    int wid = threadIdx.x >> 6;
    int lane = threadIdx.x & 63;
    size_t row = (size_t)blockIdx.x * 4 + wid;
    const float* hrow = hcat + row * 512;
    float4 h0 = *(const float4*)(hrow + lane * 8);
    float4 h1 = *(const float4*)(hrow + lane * 8 + 4);
    for (int k2 = 0; k2 < KTAG; ++k2) {
        const float* wr = Wout + (size_t)k2 * 512 + lane * 8;
        float4 w0 = *(const float4*)wr;
        float4 w1 = *(const float4*)(wr + 4);
        float p = h0.x * w0.x + h0.y * w0.y + h0.z * w0.z + h0.w * w0.w
                + h1.x * w1.x + h1.y * w1.y + h1.z * w1.z + h1.w * w1.w;
#pragma unroll
        for (int off = 32; off; off >>= 1) p += __shfl_down(p, off);
        if (lane == 0) feats[row * KTAG + k2] = p + bout[k2];
    }
}

// ---------------------------------------------------------------------------
// K4: Viterbi DP + backtrace. One wave per batch. 8-step feats prefetch ring.
// ---------------------------------------------------------------------------
__global__ __launch_bounds__(64) void viterbi_kernel(
    const float* __restrict__ feats, const float* __restrict__ trans,
    const int* __restrict__ slen, float* __restrict__ out) {
    int b = blockIdx.x;
    int lane = threadIdx.x;
    __shared__ unsigned char bp[TLEN][KTAG];

    int len = slen[b];
    float tr[KTAG];
#pragma unroll
    for (int p = 0; p < KTAG; ++p) tr[p] = 0.f;
    if (lane < KTAG) {
#pragma unroll
        for (int p = 0; p < KTAG; ++p) tr[p] = trans[lane * KTAG + p];
    }
    float tstop = (lane < KTAG) ? trans[STOP_TAG * KTAG + lane] : NEGV;
    float dp = (lane == START_TAG) ? 0.f : NEGV;

    float fb[8];
#pragma unroll
    for (int k = 0; k < 8; ++k)
        fb[k] = (lane < KTAG) ? feats[((size_t)k * BATCH + b) * KTAG + lane] : 0.f;

    for (int t0 = 0; t0 < TLEN; t0 += 8) {
#pragma unroll
        for (int u = 0; u < 8; ++u) {
            int t = t0 + u;
            float ftc = fb[u];
            int tn = t + 8;
            fb[u] = (tn < TLEN && lane < KTAG)
                        ? feats[((size_t)tn * BATCH + b) * KTAG + lane] : 0.f;
            float best = -1e30f;
            int arg = 0;
#pragma unroll
            for (int p = 0; p < KTAG; ++p) {
                float dpp = __shfl(dp, p);
                float sc = dpp + tr[p];
                if (sc > best) { best = sc; arg = p; }
            }
            bool m = (t < len);
            if (lane < KTAG) {
                dp = m ? (best + ftc) : dp;
                bp[t][lane] = (unsigned char)(m ? arg : lane);
            }
        }
    }

    float term = dp + tstop;
    float bbest = -1e30f;
    int barg = 0;
#pragma unroll
    for (int p = 0; p < KTAG; ++p) {
        float v = __shfl(term, p);
        if (v > bbest) { bbest = v; barg = p; }
    }
    if (lane == 0) {
        out[b] = bbest;
        float* path = out + BATCH + (size_t)b * TLEN;
        int tag = barg;
        for (int t = TLEN - 1; t >= 0; --t) {
            path[t] = (float)tag;
            tag = bp[t][tag];
        }
    }
}

// ---------------------------------------------------------------------------
extern "C" void kernel_launch(void* const* d_in, const int* in_sizes, int n_in,
                              void* d_out, int out_size, void* d_ws, size_t ws_size,
                              hipStream_t stream) {
    const int*   sentence = (const int*)d_in[0];
    const int*   slen     = (const int*)d_in[1];
    const float* emb      = (const float*)d_in[2];
    const float* Wf_ih    = (const float*)d_in[3];
    const float* Wf_hh    = (const float*)d_in[4];
    const float* bf_ih    = (const float*)d_in[5];
    const float* bf_hh    = (const float*)d_in[6];
    const float* Wb_ih    = (const float*)d_in[7];
    const float* Wb_hh    = (const float*)d_in[8];
    const float* bb_ih    = (const float*)d_in[9];
    const float* bb_hh    = (const float*)d_in[10];
    const float* W_out    = (const float*)d_in[11];
    const float* b_out    = (const float*)d_in[12];
    const float* trans    = (const float*)d_in[13];
    float* out = (float*)d_out;

    char* ws = (char*)d_ws;
    float* xf    = (float*)(ws);                       // 134,217,728 B
    float* xb    = (float*)(ws + 134217728ull);        // 134,217,728 B
    float* hcat  = (float*)(ws + 268435456ull);        //  67,108,864 B
    float* feats = (float*)(ws + 335544320ull);        //   1,572,864 B

    // sentinel-fill hcat: 0xFFFFFFFF = -NaN, unreachable for tanh-bounded h
    hipMemsetAsync(hcat, 0xFF, 67108864ull, stream);
    hipLaunchKernelGGL(proj_kernel, dim3(256, 16), dim3(256), 0, stream,
                       sentence, emb, Wf_ih, Wb_ih, bf_ih, bf_hh, bb_ih, bb_hh, xf, xb);
    hipLaunchKernelGGL(lstm_scan5, dim3(256), dim3(256), 0, stream,
                       xf, xb, Wf_hh, Wb_hh, hcat);
    hipLaunchKernelGGL(feats_kernel, dim3(8192), dim3(256), 0, stream,
                       hcat, W_out, b_out, feats);
    hipLaunchKernelGGL(viterbi_kernel, dim3(64), dim3(64), 0, stream,
                       feats, trans, slen, out);
}